// Round 1
// baseline (254.884 us; speedup 1.0000x reference)
//
#include <hip/hip_runtime.h>
#include <hip/hip_bf16.h>

#define PI_F 3.14159265358979323846f

__device__ __forceinline__ float2 cmul(float2 a, float2 b){
  return make_float2(fmaf(a.x, b.x, -(a.y*b.y)), fmaf(a.x, b.y, a.y*b.x));
}

// kept (unshifted) frequency indices: [0,44) U [211,256)
__device__ __forceinline__ bool keepf(int k){ return (k < 44) || (k >= 211); }

// 256-point complex FFT, radix-4 Stockham, 64 lanes (j = lane), 4 points/lane.
// Data starts in A, result ends in A (natural order). SIGN=-1 fwd, +1 inv.
// Caller must __syncthreads() after filling A. Unnormalized.
template<int SIGN>
__device__ __forceinline__ void fft256(float2* __restrict__ A, float2* __restrict__ B, int j){
  float2* src = A;
  float2* dst = B;
#pragma unroll
  for(int s = 0; s < 4; ++s){
    const int Ns = 1 << (2*s);
    const int jm = j & (Ns - 1);
    float ang = (float)SIGN * (2.0f * PI_F) * (float)jm / (float)(Ns * 4);
    float sn, cs;
    __sincosf(ang, &sn, &cs);
    float2 w1 = make_float2(cs, sn);
    float2 w2 = cmul(w1, w1);
    float2 w3 = cmul(w2, w1);
    float2 v0 = src[j];
    float2 v1 = cmul(src[j + 64],  w1);
    float2 v2 = cmul(src[j + 128], w2);
    float2 v3 = cmul(src[j + 192], w3);
    float2 t0 = make_float2(v0.x + v2.x, v0.y + v2.y);
    float2 t1 = make_float2(v0.x - v2.x, v0.y - v2.y);
    float2 t2 = make_float2(v1.x + v3.x, v1.y + v3.y);
    float2 t3 = make_float2(v1.x - v3.x, v1.y - v3.y);
    float2 y0 = make_float2(t0.x + t2.x, t0.y + t2.y);
    float2 y2 = make_float2(t0.x - t2.x, t0.y - t2.y);
    float2 y1, y3;
    if (SIGN < 0){ // forward: y1 = t1 - i*t3 ; y3 = t1 + i*t3
      y1 = make_float2(t1.x + t3.y, t1.y - t3.x);
      y3 = make_float2(t1.x - t3.y, t1.y + t3.x);
    } else {       // inverse: conjugated
      y1 = make_float2(t1.x - t3.y, t1.y + t3.x);
      y3 = make_float2(t1.x + t3.y, t1.y - t3.x);
    }
    const int idxD = ((j >> (2*s)) << (2*s + 2)) + jm; // (j/Ns)*Ns*4 + j%Ns
    dst[idxD]        = y0;
    dst[idxD + Ns]   = y1;
    dst[idxD + 2*Ns] = y2;
    dst[idxD + 3*Ns] = y3;
    float2* t = src; src = dst; dst = t;
    __syncthreads();
  }
  // after 4 swaps result is back in A
}

// K1: d = target - refer (complex), FFT along W per row, apply w-mask, store.
__global__ __launch_bounds__(256) void k_rowfft(const float* __restrict__ tgt,
                                                const float* __restrict__ ref,
                                                float2* __restrict__ dkw){
  __shared__ float2 A[4][256];
  __shared__ float2 B[4][256];
  const int wv = threadIdx.x >> 6, ln = threadIdx.x & 63;
  const int line = blockIdx.x * 4 + wv;       // 8192 lines
  const int b = line >> 8, h = line & 255;
  const size_t base0 = ((size_t)(b*2 + 0)*256 + h)*256;
  const size_t base1 = ((size_t)(b*2 + 1)*256 + h)*256;
  float4 tr = *(const float4*)(tgt + base0 + ln*4);
  float4 ti = *(const float4*)(tgt + base1 + ln*4);
  float4 rr = *(const float4*)(ref + base0 + ln*4);
  float4 ri = *(const float4*)(ref + base1 + ln*4);
  A[wv][ln*4 + 0] = make_float2(tr.x - rr.x, ti.x - ri.x);
  A[wv][ln*4 + 1] = make_float2(tr.y - rr.y, ti.y - ri.y);
  A[wv][ln*4 + 2] = make_float2(tr.z - rr.z, ti.z - ri.z);
  A[wv][ln*4 + 3] = make_float2(tr.w - rr.w, ti.w - ri.w);
  __syncthreads();
  fft256<-1>(A[wv], B[wv], ln);
  float2* out = dkw + ((size_t)b*256 + h)*256;
#pragma unroll
  for(int k = 0; k < 4; ++k){
    int w = ln*4 + k;
    float2 v = A[wv][w];
    out[w] = keepf(w) ? v : make_float2(0.f, 0.f);
  }
}

// K2: for kept columns only: FFT along H, apply h-mask, IFFT along H, in place.
__global__ __launch_bounds__(256) void k_colfft(float2* __restrict__ dkw){
  __shared__ float2 A[4][256];
  __shared__ float2 B[4][256];
  const int wv = threadIdx.x >> 6, ln = threadIdx.x & 63;
  const int idx = blockIdx.x * 4 + wv;        // 0..2847  (32 batches * 89 cols)
  const int b = idx / 89;
  const int c = idx - b*89;
  const int w = (c < 44) ? c : (c + 167);     // kept w index
  float2* col = dkw + (size_t)b*65536 + w;
#pragma unroll
  for(int k = 0; k < 4; ++k){
    int r = ln + 64*k;
    A[wv][r] = col[(size_t)r * 256];
  }
  __syncthreads();
  fft256<-1>(A[wv], B[wv], ln);
#pragma unroll
  for(int k = 0; k < 4; ++k){
    int r = ln + 64*k;
    if(!keepf(r)) A[wv][r] = make_float2(0.f, 0.f);
  }
  __syncthreads();
  fft256<1>(A[wv], B[wv], ln);
#pragma unroll
  for(int k = 0; k < 4; ++k){
    int r = ln + 64*k;
    col[(size_t)r * 256] = A[wv][r];
  }
}

// K3: IFFT along W per row, scale 1/65536, add refer -> change image planes.
__global__ __launch_bounds__(256) void k_rowifft(const float2* __restrict__ dkw,
                                                 const float* __restrict__ ref,
                                                 float* __restrict__ chg){
  __shared__ float2 A[4][256];
  __shared__ float2 B[4][256];
  const int wv = threadIdx.x >> 6, ln = threadIdx.x & 63;
  const int line = blockIdx.x * 4 + wv;
  const int b = line >> 8, h = line & 255;
  const float2* in = dkw + ((size_t)b*256 + h)*256;
#pragma unroll
  for(int k = 0; k < 4; ++k){
    int w = ln*4 + k;
    A[wv][w] = in[w];
  }
  __syncthreads();
  fft256<1>(A[wv], B[wv], ln);
  const float sc = 1.0f / 65536.0f;
  const size_t base0 = ((size_t)(b*2 + 0)*256 + h)*256;
  const size_t base1 = ((size_t)(b*2 + 1)*256 + h)*256;
  float4 rr = *(const float4*)(ref + base0 + ln*4);
  float4 ri = *(const float4*)(ref + base1 + ln*4);
  float2 v0 = A[wv][ln*4 + 0];
  float2 v1 = A[wv][ln*4 + 1];
  float2 v2 = A[wv][ln*4 + 2];
  float2 v3 = A[wv][ln*4 + 3];
  float4 o0 = make_float4(fmaf(v0.x, sc, rr.x), fmaf(v1.x, sc, rr.y),
                          fmaf(v2.x, sc, rr.z), fmaf(v3.x, sc, rr.w));
  float4 o1 = make_float4(fmaf(v0.y, sc, ri.x), fmaf(v1.y, sc, ri.y),
                          fmaf(v2.y, sc, ri.z), fmaf(v3.y, sc, ri.w));
  *(float4*)(chg + base0 + ln*4) = o0;
  *(float4*)(chg + base1 + ln*4) = o1;
}

// K4: fused conv1 (2->64) + conv2 (64->2), 3x3/pad1 each, per 16x16 output tile.
#define MIDS 72   // bf16 stride of mid channel dim (16B aligned, low bank conflict)

__device__ __forceinline__ void fma8(uint4 m, uint4 w, float& acc){
  const unsigned* mp = reinterpret_cast<const unsigned*>(&m);
  const unsigned* wp = reinterpret_cast<const unsigned*>(&w);
#pragma unroll
  for(int q = 0; q < 4; ++q){
    float m0 = __uint_as_float(mp[q] << 16);
    float m1 = __uint_as_float(mp[q] & 0xffff0000u);
    float w0 = __uint_as_float(wp[q] << 16);
    float w1 = __uint_as_float(wp[q] & 0xffff0000u);
    acc = fmaf(m0, w0, acc);
    acc = fmaf(m1, w1, acc);
  }
}

__global__ __launch_bounds__(256) void k_conv(const float* __restrict__ chg,
                                              const float* __restrict__ w1g,
                                              const float* __restrict__ b1g,
                                              const float* __restrict__ w2g,
                                              const float* __restrict__ b2g,
                                              float* __restrict__ out){
  __shared__ __align__(16) float2 in2[20][20];                 // (ch0,ch1) input tile
  __shared__ __align__(16) __hip_bfloat16 mid[18][18][MIDS];   // conv1 out, 64 ch used
  __shared__ __align__(16) __hip_bfloat16 w2l[1152];           // w2 as [oc][ky][kx][ic]
  const int tid = threadIdx.x;
  const int b   = blockIdx.y;
  const int tx0 = (blockIdx.x & 15) << 4;
  const int ty0 = (blockIdx.x >> 4) << 4;
  const float* c0 = chg + (size_t)(b*2 + 0)*65536;
  const float* c1 = chg + (size_t)(b*2 + 1)*65536;

  // stage 20x20 input tile (zero-padded at image borders)
  for(int idx = tid; idx < 400; idx += 256){
    int iy = idx / 20, ix = idx - iy*20;
    int gy = ty0 - 2 + iy, gx = tx0 - 2 + ix;
    float2 v = make_float2(0.f, 0.f);
    if((unsigned)gy < 256u && (unsigned)gx < 256u){
      v.x = c0[gy*256 + gx];
      v.y = c1[gy*256 + gx];
    }
    in2[iy][ix] = v;
  }
  // stage w2 reordered to [oc][ky][kx][ic] bf16
  for(int idx = tid; idx < 1152; idx += 256){
    int oc = idx / 576;
    int r  = idx - oc*576;
    int ky = r / 192;
    int kxic = r - ky*192;
    int kx = kxic >> 6;
    int ic = kxic & 63;
    w2l[idx] = __float2bfloat16(w2g[((oc*64 + ic)*3 + ky)*3 + kx]);
  }
  // conv1 weights for this thread's output channel into registers
  const int oc = tid & 63;
  const int g  = tid >> 6;
  float wr[18];
#pragma unroll
  for(int k = 0; k < 18; ++k) wr[k] = w1g[oc*18 + k];
  const float bias1 = b1g[oc];
  __syncthreads();

  // conv1: thread = (oc, column-group); walk 18 rows down each owned column
  for(int c = g; c < 18; c += 4){
    float2 r0[3], r1[3], r2[3];
#pragma unroll
    for(int k = 0; k < 3; ++k){ r0[k] = in2[0][c+k]; r1[k] = in2[1][c+k]; r2[k] = in2[2][c+k]; }
    const bool cin = (unsigned)(tx0 - 1 + c) < 256u;
    for(int my = 0; my < 18; ++my){
      float acc = bias1;
#pragma unroll
      for(int k = 0; k < 3; ++k){
        acc = fmaf(r0[k].x, wr[k],      acc);
        acc = fmaf(r1[k].x, wr[3 + k],  acc);
        acc = fmaf(r2[k].x, wr[6 + k],  acc);
        acc = fmaf(r0[k].y, wr[9 + k],  acc);
        acc = fmaf(r1[k].y, wr[12 + k], acc);
        acc = fmaf(r2[k].y, wr[15 + k], acc);
      }
      // positions outside the image are zero-padding for conv2, NOT conv1 values
      bool inside = cin && ((unsigned)(ty0 - 1 + my) < 256u);
      mid[my][c][oc] = __float2bfloat16(inside ? acc : 0.0f);
      if(my < 17){
#pragma unroll
        for(int k = 0; k < 3; ++k){ r0[k] = r1[k]; r1[k] = r2[k]; r2[k] = in2[my + 3][c + k]; }
      }
    }
  }
  __syncthreads();

  // conv2: thread = one output pixel, both output channels
  const int px = tid & 15, py = tid >> 4;
  float acc0 = b2g[0], acc1 = b2g[1];
#pragma unroll
  for(int ky = 0; ky < 3; ++ky){
#pragma unroll
    for(int kx = 0; kx < 3; ++kx){
      const uint4* mv  = reinterpret_cast<const uint4*>(&mid[py + ky][px + kx][0]);
      const uint4* wv0 = reinterpret_cast<const uint4*>(&w2l[(ky*3 + kx)*64]);
      const uint4* wv1 = reinterpret_cast<const uint4*>(&w2l[576 + (ky*3 + kx)*64]);
#pragma unroll
      for(int q = 0; q < 8; ++q){
        uint4 m = mv[q];
        fma8(m, wv0[q], acc0);
        fma8(m, wv1[q], acc1);
      }
    }
  }
  const int oy = ty0 + py, ox = tx0 + px;
  out[((size_t)(b*2 + 0)*256 + oy)*256 + ox] = acc0;
  out[((size_t)(b*2 + 1)*256 + oy)*256 + ox] = acc1;
}

extern "C" void kernel_launch(void* const* d_in, const int* in_sizes, int n_in,
                              void* d_out, int out_size, void* d_ws, size_t ws_size,
                              hipStream_t stream) {
  const float* tgt = (const float*)d_in[0];
  const float* ref = (const float*)d_in[1];
  const float* w1  = (const float*)d_in[2];
  const float* b1  = (const float*)d_in[3];
  const float* w2  = (const float*)d_in[4];
  const float* b2  = (const float*)d_in[5];
  float* out = (float*)d_out;

  // ws layout: [0, 16.78MB) complex k-space scratch; [16.78MB, 33.55MB) change image
  float2* dkw = (float2*)d_ws;                                   // 32*256*256 float2
  float*  chg = (float*)((char*)d_ws + (size_t)32*65536*sizeof(float2)); // 32*2*256*256 f32

  k_rowfft <<<2048, 256, 0, stream>>>(tgt, ref, dkw);
  k_colfft <<<712,  256, 0, stream>>>(dkw);        // 32*89/4 waves
  k_rowifft<<<2048, 256, 0, stream>>>(dkw, ref, chg);
  dim3 gc(256, 32);
  k_conv   <<<gc,   256, 0, stream>>>(chg, w1, b1, w2, b2, out);
}

// Round 2
// 154.865 us; speedup vs baseline: 1.6458x; 1.6458x over previous
//
#include <hip/hip_runtime.h>
#include <hip/hip_bf16.h>

#define PI_F 3.14159265358979323846f
#define RING_N 1028

__device__ __forceinline__ float2 cmul(float2 a, float2 b){
  return make_float2(fmaf(a.x, b.x, -(a.y*b.y)), fmaf(a.x, b.y, a.y*b.x));
}

// kept (unshifted) frequency indices: [0,44) U [211,256)
__device__ __forceinline__ bool keepf(int k){ return (k < 44) || (k >= 211); }

// 256-point complex FFT, radix-4 Stockham, 64 lanes (j = lane), 4 points/lane.
// Data starts in A, result ends in A (natural order). SIGN=-1 fwd, +1 inv.
// Caller must __syncthreads() after filling A. Unnormalized.
template<int SIGN>
__device__ __forceinline__ void fft256(float2* __restrict__ A, float2* __restrict__ B, int j){
  float2* src = A;
  float2* dst = B;
#pragma unroll
  for(int s = 0; s < 4; ++s){
    const int Ns = 1 << (2*s);
    const int jm = j & (Ns - 1);
    float ang = (float)SIGN * (2.0f * PI_F) * (float)jm / (float)(Ns * 4);
    float sn, cs;
    __sincosf(ang, &sn, &cs);
    float2 w1 = make_float2(cs, sn);
    float2 w2 = cmul(w1, w1);
    float2 w3 = cmul(w2, w1);
    float2 v0 = src[j];
    float2 v1 = cmul(src[j + 64],  w1);
    float2 v2 = cmul(src[j + 128], w2);
    float2 v3 = cmul(src[j + 192], w3);
    float2 t0 = make_float2(v0.x + v2.x, v0.y + v2.y);
    float2 t1 = make_float2(v0.x - v2.x, v0.y - v2.y);
    float2 t2 = make_float2(v1.x + v3.x, v1.y + v3.y);
    float2 t3 = make_float2(v1.x - v3.x, v1.y - v3.y);
    float2 y0 = make_float2(t0.x + t2.x, t0.y + t2.y);
    float2 y2 = make_float2(t0.x - t2.x, t0.y - t2.y);
    float2 y1, y3;
    if (SIGN < 0){
      y1 = make_float2(t1.x + t3.y, t1.y - t3.x);
      y3 = make_float2(t1.x - t3.y, t1.y + t3.x);
    } else {
      y1 = make_float2(t1.x - t3.y, t1.y + t3.x);
      y3 = make_float2(t1.x + t3.y, t1.y - t3.x);
    }
    const int idxD = ((j >> (2*s)) << (2*s + 2)) + jm;
    dst[idxD]        = y0;
    dst[idxD + Ns]   = y1;
    dst[idxD + 2*Ns] = y2;
    dst[idxD + 3*Ns] = y3;
    float2* t = src; src = dst; dst = t;
    __syncthreads();
  }
}

// K1: d = target - refer (complex), FFT along W per row, apply w-mask, store.
__global__ __launch_bounds__(256) void k_rowfft(const float* __restrict__ tgt,
                                                const float* __restrict__ ref,
                                                float2* __restrict__ dkw){
  __shared__ float2 A[4][256];
  __shared__ float2 B[4][256];
  const int wv = threadIdx.x >> 6, ln = threadIdx.x & 63;
  const int line = blockIdx.x * 4 + wv;
  const int b = line >> 8, h = line & 255;
  const size_t base0 = ((size_t)(b*2 + 0)*256 + h)*256;
  const size_t base1 = ((size_t)(b*2 + 1)*256 + h)*256;
  float4 tr = *(const float4*)(tgt + base0 + ln*4);
  float4 ti = *(const float4*)(tgt + base1 + ln*4);
  float4 rr = *(const float4*)(ref + base0 + ln*4);
  float4 ri = *(const float4*)(ref + base1 + ln*4);
  A[wv][ln*4 + 0] = make_float2(tr.x - rr.x, ti.x - ri.x);
  A[wv][ln*4 + 1] = make_float2(tr.y - rr.y, ti.y - ri.y);
  A[wv][ln*4 + 2] = make_float2(tr.z - rr.z, ti.z - ri.z);
  A[wv][ln*4 + 3] = make_float2(tr.w - rr.w, ti.w - ri.w);
  __syncthreads();
  fft256<-1>(A[wv], B[wv], ln);
  float2* out = dkw + ((size_t)b*256 + h)*256;
#pragma unroll
  for(int k = 0; k < 4; ++k){
    int w = ln*4 + k;
    float2 v = A[wv][w];
    out[w] = keepf(w) ? v : make_float2(0.f, 0.f);
  }
}

// K2: for kept columns only: FFT along H, apply h-mask, IFFT along H, in place.
__global__ __launch_bounds__(256) void k_colfft(float2* __restrict__ dkw){
  __shared__ float2 A[4][256];
  __shared__ float2 B[4][256];
  const int wv = threadIdx.x >> 6, ln = threadIdx.x & 63;
  const int idx = blockIdx.x * 4 + wv;
  const int b = idx / 89;
  const int c = idx - b*89;
  const int w = (c < 44) ? c : (c + 167);
  float2* col = dkw + (size_t)b*65536 + w;
#pragma unroll
  for(int k = 0; k < 4; ++k){
    int r = ln + 64*k;
    A[wv][r] = col[(size_t)r * 256];
  }
  __syncthreads();
  fft256<-1>(A[wv], B[wv], ln);
#pragma unroll
  for(int k = 0; k < 4; ++k){
    int r = ln + 64*k;
    if(!keepf(r)) A[wv][r] = make_float2(0.f, 0.f);
  }
  __syncthreads();
  fft256<1>(A[wv], B[wv], ln);
#pragma unroll
  for(int k = 0; k < 4; ++k){
    int r = ln + 64*k;
    col[(size_t)r * 256] = A[wv][r];
  }
}

// K3: IFFT along W per row, scale 1/65536, add refer -> change image planes.
__global__ __launch_bounds__(256) void k_rowifft(const float2* __restrict__ dkw,
                                                 const float* __restrict__ ref,
                                                 float* __restrict__ chg){
  __shared__ float2 A[4][256];
  __shared__ float2 B[4][256];
  const int wv = threadIdx.x >> 6, ln = threadIdx.x & 63;
  const int line = blockIdx.x * 4 + wv;
  const int b = line >> 8, h = line & 255;
  const float2* in = dkw + ((size_t)b*256 + h)*256;
#pragma unroll
  for(int k = 0; k < 4; ++k){
    int w = ln*4 + k;
    A[wv][w] = in[w];
  }
  __syncthreads();
  fft256<1>(A[wv], B[wv], ln);
  const float sc = 1.0f / 65536.0f;
  const size_t base0 = ((size_t)(b*2 + 0)*256 + h)*256;
  const size_t base1 = ((size_t)(b*2 + 1)*256 + h)*256;
  float4 rr = *(const float4*)(ref + base0 + ln*4);
  float4 ri = *(const float4*)(ref + base1 + ln*4);
  float2 v0 = A[wv][ln*4 + 0];
  float2 v1 = A[wv][ln*4 + 1];
  float2 v2 = A[wv][ln*4 + 2];
  float2 v3 = A[wv][ln*4 + 3];
  float4 o0 = make_float4(fmaf(v0.x, sc, rr.x), fmaf(v1.x, sc, rr.y),
                          fmaf(v2.x, sc, rr.z), fmaf(v3.x, sc, rr.w));
  float4 o1 = make_float4(fmaf(v0.y, sc, ri.x), fmaf(v1.y, sc, ri.y),
                          fmaf(v2.y, sc, ri.z), fmaf(v3.y, sc, ri.w));
  *(float4*)(chg + base0 + ln*4) = o0;
  *(float4*)(chg + base1 + ln*4) = o1;
}

// exterior-ring position -> (gy,gx); r in [0,RING_N)
__device__ __forceinline__ int ring_index(int gy, int gx){
  if(gy == -1)  return gx + 1;          // gx in [-1,256]
  if(gy == 256) return 258 + gx + 1;
  if(gx == -1)  return 516 + gy;        // gy in [0,255]
  return 772 + gy;                       // gx == 256
}

// K_prep: blockIdx.x<257: mid_full on the exterior ring (with b1, zero-padded x).
//         blockIdx.x==257 (y==0): composite 5x5 weights W_eff + b_eff.
__global__ __launch_bounds__(256) void k_prep(const float* __restrict__ chg,
                                              const float* __restrict__ w1g,
                                              const float* __restrict__ b1g,
                                              const float* __restrict__ w2g,
                                              const float* __restrict__ b2g,
                                              float* __restrict__ ring,
                                              float* __restrict__ wefg){
  const int tid = threadIdx.x;
  if(blockIdx.x == 257){
    if(blockIdx.y != 0) return;
    if(tid < 100){
      const int t = tid;
      const int ux = t % 5, uy = (t/5) % 5, ic = (t/25) & 1, oc = t/50;
      float acc = 0.f;
      for(int mc = 0; mc < 64; ++mc){
        for(int dy = 0; dy < 3; ++dy){
          int ky = uy - dy; if((unsigned)ky >= 3u) continue;
          for(int dx = 0; dx < 3; ++dx){
            int kx = ux - dx; if((unsigned)kx >= 3u) continue;
            acc = fmaf(w2g[((oc*64+mc)*3+dy)*3+dx], w1g[((mc*2+ic)*3+ky)*3+kx], acc);
          }
        }
      }
      wefg[t] = acc;
    } else if(tid < 102){
      const int oc = tid - 100;
      float acc = b2g[oc];
      for(int mc = 0; mc < 64; ++mc){
        float s = 0.f;
        for(int d = 0; d < 9; ++d) s += w2g[(oc*64+mc)*9 + d];
        acc = fmaf(s, b1g[mc], acc);
      }
      wefg[tid] = acc;
    }
    return;
  }
  // exterior ring mid_full
  const int pos = blockIdx.x*4 + (tid >> 6);
  const int mc  = tid & 63;
  const int b   = blockIdx.y;
  int gy, gx;
  if(pos < 258){ gy = -1;  gx = pos - 1; }
  else if(pos < 516){ gy = 256; gx = pos - 259; }
  else if(pos < 772){ gx = -1;  gy = pos - 516; }
  else { gx = 256; gy = pos - 772; }
  float acc = b1g[mc];
  const float* c0 = chg + (size_t)(b*2 + 0)*65536;
  const float* c1 = chg + (size_t)(b*2 + 1)*65536;
  for(int ky = 0; ky < 3; ++ky){
    int sy = gy + ky - 1; if((unsigned)sy >= 256u) continue;
    for(int kx = 0; kx < 3; ++kx){
      int sx = gx + kx - 1; if((unsigned)sx >= 256u) continue;
      acc = fmaf(w1g[((mc*2+0)*3+ky)*3+kx], c0[sy*256+sx], acc);
      acc = fmaf(w1g[((mc*2+1)*3+ky)*3+kx], c1[sy*256+sx], acc);
    }
  }
  ring[((size_t)b*RING_N + pos)*64 + mc] = acc;
}

// K5: composite 5x5 conv (2->2) + exact border fixup.
__global__ __launch_bounds__(256) void k_conv5(const float* __restrict__ chg,
                                               const float* __restrict__ ring,
                                               const float* __restrict__ wefg,
                                               const float* __restrict__ w2g,
                                               float* __restrict__ out){
  __shared__ __align__(16) float2 xt[20][20];
  __shared__ float wef[102];
  __shared__ float w2s[9][64][2];
  const int tid = threadIdx.x;
  const int b   = blockIdx.y;
  const int tx0 = (blockIdx.x & 15) << 4;
  const int ty0 = (blockIdx.x >> 4) << 4;
  const float* c0 = chg + (size_t)(b*2 + 0)*65536;
  const float* c1 = chg + (size_t)(b*2 + 1)*65536;
  for(int idx = tid; idx < 400; idx += 256){
    int iy = idx / 20, ix = idx - iy*20;
    int gy = ty0 - 2 + iy, gx = tx0 - 2 + ix;
    float2 v = make_float2(0.f, 0.f);
    if((unsigned)gy < 256u && (unsigned)gx < 256u){
      v.x = c0[gy*256 + gx];
      v.y = c1[gy*256 + gx];
    }
    xt[iy][ix] = v;
  }
  if(tid < 102) wef[tid] = wefg[tid];
  const bool border = (tx0 == 0) || (ty0 == 0) || (tx0 == 240) || (ty0 == 240);
  if(border){
    for(int idx = tid; idx < 1152; idx += 256){
      int oc = idx & 1, mc = (idx >> 1) & 63, d = idx >> 7;
      w2s[d][mc][oc] = w2g[(oc*64 + mc)*9 + d];
    }
  }
  __syncthreads();
  const int px = tid & 15, py = tid >> 4;
  float a0 = wef[100], a1 = wef[101];
#pragma unroll
  for(int uy = 0; uy < 5; ++uy){
#pragma unroll
    for(int ux = 0; ux < 5; ++ux){
      float2 v = xt[py + uy][px + ux];
      a0 = fmaf(v.x, wef[uy*5 + ux],      a0);
      a0 = fmaf(v.y, wef[25 + uy*5 + ux], a0);
      a1 = fmaf(v.x, wef[50 + uy*5 + ux], a1);
      a1 = fmaf(v.y, wef[75 + uy*5 + ux], a1);
    }
  }
  const int oy = ty0 + py, ox = tx0 + px;
  if(border && (oy == 0 || oy == 255 || ox == 0 || ox == 255)){
    for(int d = 0; d < 9; ++d){
      int gy = oy + d/3 - 1, gx = ox + d%3 - 1;
      if((unsigned)gy < 256u && (unsigned)gx < 256u) continue;
      int r = ring_index(gy, gx);
      const float* rv = ring + ((size_t)b*RING_N + r)*64;
      for(int mc = 0; mc < 64; ++mc){
        float v = rv[mc];
        a0 = fmaf(-w2s[d][mc][0], v, a0);
        a1 = fmaf(-w2s[d][mc][1], v, a1);
      }
    }
  }
  out[((size_t)(b*2 + 0)*256 + oy)*256 + ox] = a0;
  out[((size_t)(b*2 + 1)*256 + oy)*256 + ox] = a1;
}

extern "C" void kernel_launch(void* const* d_in, const int* in_sizes, int n_in,
                              void* d_out, int out_size, void* d_ws, size_t ws_size,
                              hipStream_t stream) {
  const float* tgt = (const float*)d_in[0];
  const float* ref = (const float*)d_in[1];
  const float* w1  = (const float*)d_in[2];
  const float* b1  = (const float*)d_in[3];
  const float* w2  = (const float*)d_in[4];
  const float* b2  = (const float*)d_in[5];
  float* out = (float*)d_out;

  // ws layout:
  //   [0, 16.78MB)        dkw (complex k-space), later reused: ring @0 (8.42MB), wefg @12MB
  //   [16.78MB, 33.55MB)  chg (change image, 2 f32 planes per batch)
  float2* dkw  = (float2*)d_ws;
  float*  chg  = (float*)((char*)d_ws + (size_t)32*65536*sizeof(float2));
  float*  ring = (float*)d_ws;
  float*  wefg = (float*)((char*)d_ws + (size_t)12*1024*1024);

  k_rowfft <<<2048, 256, 0, stream>>>(tgt, ref, dkw);
  k_colfft <<<712,  256, 0, stream>>>(dkw);
  k_rowifft<<<2048, 256, 0, stream>>>(dkw, ref, chg);
  dim3 gp(258, 32);
  k_prep   <<<gp,   256, 0, stream>>>(chg, w1, b1, w2, b2, ring, wefg);
  dim3 gc(256, 32);
  k_conv5  <<<gc,   256, 0, stream>>>(chg, ring, wefg, w2, out);
}

// Round 3
// 118.607 us; speedup vs baseline: 2.1490x; 1.3057x over previous
//
#include <hip/hip_runtime.h>

#define PI_F 3.14159265358979323846f
#define SC (1.0f/65536.0f)

__device__ __forceinline__ float2 cmul(float2 a, float2 b){
  return make_float2(fmaf(a.x, b.x, -(a.y*b.y)), fmaf(a.x, b.y, a.y*b.x));
}

// kept (unshifted) frequency indices: [0,44) U [211,256); compact c: w<44 -> c=w, w>=211 -> c=w-167
__device__ __forceinline__ bool keepf(int k){ return (k < 44) || (k >= 211); }

// 256-point complex FFT, radix-4 Stockham, 64 lanes (j = lane), 4 points/lane.
// Data starts in A, ends in A (natural order). SIGN=-1 fwd, +1 inv. Unnormalized.
// Caller must __syncthreads() after filling A. 5 block barriers inside (4 stages).
template<int SIGN>
__device__ __forceinline__ void fft256(float2* __restrict__ A, float2* __restrict__ B, int j){
  float2* src = A;
  float2* dst = B;
#pragma unroll
  for(int s = 0; s < 4; ++s){
    const int Ns = 1 << (2*s);
    const int jm = j & (Ns - 1);
    float ang = (float)SIGN * (2.0f * PI_F) * (float)jm / (float)(Ns * 4);
    float sn, cs;
    __sincosf(ang, &sn, &cs);
    float2 w1 = make_float2(cs, sn);
    float2 w2 = cmul(w1, w1);
    float2 w3 = cmul(w2, w1);
    float2 v0 = src[j];
    float2 v1 = cmul(src[j + 64],  w1);
    float2 v2 = cmul(src[j + 128], w2);
    float2 v3 = cmul(src[j + 192], w3);
    float2 t0 = make_float2(v0.x + v2.x, v0.y + v2.y);
    float2 t1 = make_float2(v0.x - v2.x, v0.y - v2.y);
    float2 t2 = make_float2(v1.x + v3.x, v1.y + v3.y);
    float2 t3 = make_float2(v1.x - v3.x, v1.y - v3.y);
    float2 y0 = make_float2(t0.x + t2.x, t0.y + t2.y);
    float2 y2 = make_float2(t0.x - t2.x, t0.y - t2.y);
    float2 y1, y3;
    if (SIGN < 0){
      y1 = make_float2(t1.x + t3.y, t1.y - t3.x);
      y3 = make_float2(t1.x - t3.y, t1.y + t3.x);
    } else {
      y1 = make_float2(t1.x - t3.y, t1.y + t3.x);
      y3 = make_float2(t1.x + t3.y, t1.y - t3.x);
    }
    const int idxD = ((j >> (2*s)) << (2*s + 2)) + jm;
    dst[idxD]        = y0;
    dst[idxD + Ns]   = y1;
    dst[idxD + 2*Ns] = y2;
    dst[idxD + 3*Ns] = y3;
    float2* t = src; src = dst; dst = t;
    __syncthreads();
  }
}

// K0: composite weights. wbuf[0..100) = Weff[oc][ic][uy][ux]; [100..102) = beff;
//     [102..426) = G[oc][ic][d][k9]; [426..444) = Cb[oc][d].
__global__ __launch_bounds__(512) void k_wprep(const float* __restrict__ w1g,
                                               const float* __restrict__ b1g,
                                               const float* __restrict__ w2g,
                                               const float* __restrict__ b2g,
                                               float* __restrict__ wbuf){
  const int t = threadIdx.x;
  if(t < 100){
    const int ux = t % 5, uy = (t/5) % 5, ic = (t/25) & 1, oc = t/50;
    float acc = 0.f;
    for(int mc = 0; mc < 64; ++mc)
      for(int dy = 0; dy < 3; ++dy){
        int ky = uy - dy; if((unsigned)ky >= 3u) continue;
        for(int dx = 0; dx < 3; ++dx){
          int kx = ux - dx; if((unsigned)kx >= 3u) continue;
          acc = fmaf(w2g[((oc*64+mc)*3+dy)*3+dx], w1g[((mc*2+ic)*3+ky)*3+kx], acc);
        }
      }
    wbuf[t] = acc;
  } else if(t < 102){
    const int oc = t - 100;
    float acc = b2g[oc];
    for(int mc = 0; mc < 64; ++mc){
      float s = 0.f;
      for(int d = 0; d < 9; ++d) s += w2g[(oc*64+mc)*9 + d];
      acc = fmaf(s, b1g[mc], acc);
    }
    wbuf[t] = acc;
  } else if(t < 426){
    const int g = t - 102;
    const int oc = g / 162, r1 = g - oc*162;
    const int ic = r1 / 81,  r2 = r1 - ic*81;
    const int d  = r2 / 9,   k9 = r2 - d*9;
    float acc = 0.f;
    for(int mc = 0; mc < 64; ++mc)
      acc = fmaf(w2g[(oc*64+mc)*9 + d], w1g[(mc*2+ic)*9 + k9], acc);
    wbuf[t] = acc;
  } else if(t < 444){
    const int i = t - 426, oc = i / 9, d = i - oc*9;
    float acc = 0.f;
    for(int mc = 0; mc < 64; ++mc)
      acc = fmaf(w2g[(oc*64+mc)*9 + d], b1g[mc], acc);
    wbuf[t] = acc;
  }
}

// K1: d = target - refer, row FFT, keep 89 w, write compact TRANSPOSED dkwT[b][c][h].
__global__ __launch_bounds__(256) void k_rowfft(const float* __restrict__ tgt,
                                                const float* __restrict__ ref,
                                                float2* __restrict__ dkwT){
  __shared__ float2 A[4][256];
  __shared__ float2 B[4][256];
  const int wv = threadIdx.x >> 6, ln = threadIdx.x & 63;
  const int line = blockIdx.x*4 + wv;
  const int b = line >> 8, h = line & 255;
  const size_t base0 = ((size_t)(b*2 + 0)*256 + h)*256;
  const size_t base1 = ((size_t)(b*2 + 1)*256 + h)*256;
  float4 tr = *(const float4*)(tgt + base0 + ln*4);
  float4 ti = *(const float4*)(tgt + base1 + ln*4);
  float4 rr = *(const float4*)(ref + base0 + ln*4);
  float4 ri = *(const float4*)(ref + base1 + ln*4);
  A[wv][ln*4 + 0] = make_float2(tr.x - rr.x, ti.x - ri.x);
  A[wv][ln*4 + 1] = make_float2(tr.y - rr.y, ti.y - ri.y);
  A[wv][ln*4 + 2] = make_float2(tr.z - rr.z, ti.z - ri.z);
  A[wv][ln*4 + 3] = make_float2(tr.w - rr.w, ti.w - ri.w);
  __syncthreads();
  fft256<-1>(A[wv], B[wv], ln);
  // cooperative transposed compact write: 89 c * 4 h, 32B chunks
  const int b0 = (blockIdx.x*4) >> 8;
  const int h0 = (blockIdx.x*4) & 255;
  for(int idx = threadIdx.x; idx < 356; idx += 256){
    const int c = idx >> 2, hh = idx & 3;
    const int w = (c < 44) ? c : (c + 167);
    dkwT[(size_t)(b0*89 + c)*256 + h0 + hh] = A[hh][w];
  }
}

// K2: per kept column: FFT along H, mask, IFFT. Read dkwT rows, write dkwC[b][h][c].
__global__ __launch_bounds__(256) void k_colfft(const float2* __restrict__ dkwT,
                                                float2* __restrict__ dkwC){
  __shared__ float2 A[4][256];
  __shared__ float2 B[4][256];
  const int wv = threadIdx.x >> 6, ln = threadIdx.x & 63;
  const int lineIdx = blockIdx.x*4 + wv;   // 2848 total = b*89 + c
  const float4* src = (const float4*)(dkwT + (size_t)lineIdx*256);
  float4 p0 = src[ln];
  float4 p1 = src[ln + 64];
  A[wv][2*ln + 0]   = make_float2(p0.x, p0.y);
  A[wv][2*ln + 1]   = make_float2(p0.z, p0.w);
  A[wv][2*ln + 128] = make_float2(p1.x, p1.y);
  A[wv][2*ln + 129] = make_float2(p1.z, p1.w);
  __syncthreads();
  fft256<-1>(A[wv], B[wv], ln);
#pragma unroll
  for(int k = 0; k < 4; ++k){
    int r = ln + 64*k;
    if(!keepf(r)) A[wv][r] = make_float2(0.f, 0.f);
  }
  __syncthreads();
  fft256<1>(A[wv], B[wv], ln);
  // cooperative write back, compact row-major
  for(int idx = threadIdx.x; idx < 1024; idx += 256){
    const int cw = idx & 3, h = idx >> 2;
    const int li = blockIdx.x*4 + cw;
    const int bb = li / 89, cc = li - bb*89;
    dkwC[((size_t)bb*256 + h)*89 + cc] = A[cw][h];
  }
}

// K3: per 16-row strip: row-IFFT 20 rows into LDS (+refer), 5x5 composite conv,
//     self-contained border fixup via G/Cb. chg never goes to HBM.
__global__ __launch_bounds__(256) void k_strip(const float2* __restrict__ dkwC,
                                               const float* __restrict__ ref,
                                               const float* __restrict__ wb,
                                               float* __restrict__ out){
  __shared__ float2 strip[20][264];   // x index = image_x + 2, valid [0,260)
  __shared__ float2 Bsc[4][256];
  __shared__ float wefs[102];
  __shared__ float Gs[324];
  __shared__ float Cbs[18];
  const int tid = threadIdx.x, wv = tid >> 6, ln = tid & 63;
  const int b = blockIdx.y, y0 = blockIdx.x * 16;

  for(int i = tid; i < 444; i += 256){
    float v = wb[i];
    if(i < 102) wefs[i] = v;
    else if(i < 426) Gs[i - 102] = v;
    else Cbs[i - 426] = v;
  }

  // ---- row IFFT phase: 5 rows per wave, barriers uniform across waves ----
  for(int i = 0; i < 5; ++i){
    const int sr = wv*5 + i;
    const int gy = y0 - 2 + sr;
    const bool gv = ((unsigned)gy < 256u);
    const float2* row = dkwC + ((size_t)b*256 + (gv ? gy : 0))*89;
#pragma unroll
    for(int k = 0; k < 4; ++k){
      const int w = ln*4 + k;
      const int c = (w < 44) ? w : ((w >= 211) ? (w - 167) : -1);
      float2 v = make_float2(0.f, 0.f);
      if(gv && c >= 0) v = row[c];
      strip[sr][2 + w] = v;
    }
    if(ln < 2){
      strip[sr][ln] = make_float2(0.f, 0.f);
      strip[sr][258 + ln] = make_float2(0.f, 0.f);
    }
    __syncthreads();
    fft256<1>(&strip[sr][2], Bsc[wv], ln);
    if(gv){
      const size_t base0 = ((size_t)(b*2 + 0)*256 + gy)*256;
      const size_t base1 = ((size_t)(b*2 + 1)*256 + gy)*256;
      float4 rr = *(const float4*)(ref + base0 + ln*4);
      float4 ri = *(const float4*)(ref + base1 + ln*4);
      float2 v0 = strip[sr][2 + ln*4 + 0];
      float2 v1 = strip[sr][2 + ln*4 + 1];
      float2 v2 = strip[sr][2 + ln*4 + 2];
      float2 v3 = strip[sr][2 + ln*4 + 3];
      strip[sr][2 + ln*4 + 0] = make_float2(fmaf(v0.x, SC, rr.x), fmaf(v0.y, SC, ri.x));
      strip[sr][2 + ln*4 + 1] = make_float2(fmaf(v1.x, SC, rr.y), fmaf(v1.y, SC, ri.y));
      strip[sr][2 + ln*4 + 2] = make_float2(fmaf(v2.x, SC, rr.z), fmaf(v2.y, SC, ri.z));
      strip[sr][2 + ln*4 + 3] = make_float2(fmaf(v3.x, SC, rr.w), fmaf(v3.y, SC, ri.w));
    }
  }
  __syncthreads();

  // ---- conv phase: thread = (py, px0), pixels ox = px0 + 16j ----
  const int py = tid >> 4, px0 = tid & 15;
  const int oy = y0 + py;
  for(int j = 0; j < 16; ++j){
    const int ox = px0 + 16*j;
    float a0 = wefs[100], a1 = wefs[101];
#pragma unroll
    for(int uy = 0; uy < 5; ++uy){
#pragma unroll
      for(int ux = 0; ux < 5; ++ux){
        const float2 v = strip[py + uy][ox + ux];
        const int wi = uy*5 + ux;
        a0 = fmaf(v.x, wefs[wi],      fmaf(v.y, wefs[25 + wi], a0));
        a1 = fmaf(v.x, wefs[50 + wi], fmaf(v.y, wefs[75 + wi], a1));
      }
    }
    if(oy != 0 && oy != 255 && ox != 0 && ox != 255){
      out[((size_t)(b*2 + 0)*256 + oy)*256 + ox] = a0;
      out[((size_t)(b*2 + 1)*256 + oy)*256 + ox] = a1;
    }
  }

  // ---- border fixup: full recompute + G/Cb correction, all from strip LDS ----
  const int nb = 32 + ((y0 == 0) ? 254 : 0) + ((y0 == 240) ? 254 : 0);
  for(int idx = tid; idx < nb; idx += 256){
    int py2, ox2;
    if(idx < 32){ py2 = idx >> 1; ox2 = (idx & 1) ? 255 : 0; }
    else {
      int e = idx - 32;
      if(y0 == 0 && e < 254){ py2 = 0; ox2 = 1 + e; }
      else { if(y0 == 0) e -= 254; py2 = 15; ox2 = 1 + e; }
    }
    const int oy2 = y0 + py2;
    float a0 = wefs[100], a1 = wefs[101];
#pragma unroll
    for(int uy = 0; uy < 5; ++uy)
#pragma unroll
      for(int ux = 0; ux < 5; ++ux){
        const float2 v = strip[py2 + uy][ox2 + ux];
        const int wi = uy*5 + ux;
        a0 = fmaf(v.x, wefs[wi],      fmaf(v.y, wefs[25 + wi], a0));
        a1 = fmaf(v.x, wefs[50 + wi], fmaf(v.y, wefs[75 + wi], a1));
      }
    for(int dy = 0; dy < 3; ++dy)
      for(int dx = 0; dx < 3; ++dx){
        const int gy2 = oy2 + dy - 1, gx2 = ox2 + dx - 1;
        if((unsigned)gy2 < 256u && (unsigned)gx2 < 256u) continue;
        const int d = dy*3 + dx;
        float c0 = Cbs[d], c1 = Cbs[9 + d];
        for(int ky = 0; ky < 3; ++ky){
          const int sy = gy2 + ky - 1;
          if((unsigned)sy >= 256u) continue;
          const int sr2 = sy - y0 + 2;
          for(int kx = 0; kx < 3; ++kx){
            const int sx = gx2 + kx - 1;
            if((unsigned)sx >= 256u) continue;
            const float2 v = strip[sr2][2 + sx];
            const int k9 = ky*3 + kx;
            c0 += Gs[0*81 + d*9 + k9]*v.x + Gs[1*81 + d*9 + k9]*v.y;
            c1 += Gs[2*81 + d*9 + k9]*v.x + Gs[3*81 + d*9 + k9]*v.y;
          }
        }
        a0 -= c0; a1 -= c1;
      }
    out[((size_t)(b*2 + 0)*256 + oy2)*256 + ox2] = a0;
    out[((size_t)(b*2 + 1)*256 + oy2)*256 + ox2] = a1;
  }
}

extern "C" void kernel_launch(void* const* d_in, const int* in_sizes, int n_in,
                              void* d_out, int out_size, void* d_ws, size_t ws_size,
                              hipStream_t stream) {
  const float* tgt = (const float*)d_in[0];
  const float* ref = (const float*)d_in[1];
  const float* w1  = (const float*)d_in[2];
  const float* b1  = (const float*)d_in[3];
  const float* w2  = (const float*)d_in[4];
  const float* b2  = (const float*)d_in[5];
  float* out = (float*)d_out;

  // ws: dkwT @0 (5.84MB), dkwC @8MB (5.84MB), wbuf @16MB (444 f32)
  float2* dkwT = (float2*)d_ws;
  float2* dkwC = (float2*)((char*)d_ws + (size_t)8*1024*1024);
  float*  wbuf = (float*)((char*)d_ws + (size_t)16*1024*1024);

  k_wprep <<<1,    512, 0, stream>>>(w1, b1, w2, b2, wbuf);
  k_rowfft<<<2048, 256, 0, stream>>>(tgt, ref, dkwT);
  k_colfft<<<712,  256, 0, stream>>>(dkwT, dkwC);
  dim3 gs(16, 32);
  k_strip <<<gs,   256, 0, stream>>>(dkwC, ref, wbuf, out);
}